// Round 3
// baseline (494.974 us; speedup 1.0000x reference)
//
#include <hip/hip_runtime.h>
#include <hip/hip_bf16.h>

#define N_NODES 65536
#define DIM 512
#define N_EDGES 524288
#define BN_EPS 1e-5f
#define NORM_EPS 1e-6f

typedef __attribute__((ext_vector_type(8))) short short8;
typedef __attribute__((ext_vector_type(4))) float f32x4;

static __device__ __forceinline__ unsigned f2bf(float f) {
    union { float f; unsigned u; } c; c.f = f;
    unsigned u = c.u;
    return (u + 0x7fffu + ((u >> 16) & 1u)) >> 16;
}
static __device__ __forceinline__ float bf16lo(unsigned u) {
    union { unsigned u; float f; } c; c.u = u << 16; return c.f;
}
static __device__ __forceinline__ float bf16hi(unsigned u) {
    union { unsigned u; float f; } c; c.u = u & 0xffff0000u; return c.f;
}
static __device__ __forceinline__ uint4 pack8(float4 a, float4 b) {
    uint4 o;
    o.x = f2bf(a.x) | (f2bf(a.y) << 16);
    o.y = f2bf(a.z) | (f2bf(a.w) << 16);
    o.z = f2bf(b.x) | (f2bf(b.y) << 16);
    o.w = f2bf(b.z) | (f2bf(b.w) << 16);
    return o;
}

// ---------------- fp32 -> bf16 convert (8 elems/thread) ----------------
__global__ void convert_kernel(const float* __restrict__ src,
                               unsigned short* __restrict__ dst, int n8) {
    int i = blockIdx.x * blockDim.x + threadIdx.x;
    if (i < n8) {
        const float4* s = (const float4*)src + i * 2;
        float4 f0 = s[0], f1 = s[1];
        ((uint4*)dst)[i] = pack8(f0, f1);
    }
}

// ---------------- CSR build ----------------
__global__ void hist_kernel(const int* __restrict__ src, int* __restrict__ counts) {
    int e = blockIdx.x * blockDim.x + threadIdx.x;
    if (e < N_EDGES) atomicAdd(&counts[src[e]], 1);
}

__global__ void scan_partial(const int* __restrict__ counts, int* __restrict__ partials) {
    __shared__ int ws[4];
    int t = threadIdx.x;
    int v = counts[blockIdx.x * 256 + t];
#pragma unroll
    for (int d = 1; d < 64; d <<= 1) v += __shfl_xor(v, d);
    if ((t & 63) == 0) ws[t >> 6] = v;
    __syncthreads();
    if (t == 0) partials[blockIdx.x] = ws[0] + ws[1] + ws[2] + ws[3];
}

__global__ void scan_base(int* __restrict__ partials) {
    __shared__ int lds[256];
    int t = threadIdx.x;
    int v = partials[t];
    lds[t] = v;
    __syncthreads();
    for (int d = 1; d < 256; d <<= 1) {
        int mine = lds[t];
        int add = (t >= d) ? lds[t - d] : 0;
        __syncthreads();
        lds[t] = mine + add;
        __syncthreads();
    }
    partials[t] = lds[t] - v;   // exclusive
}

__global__ void scan_final(const int* __restrict__ counts,
                           const int* __restrict__ partials,
                           int* __restrict__ offsets, int* __restrict__ cursor) {
    __shared__ int lds[256];
    int t = threadIdx.x, b = blockIdx.x;
    int v = counts[b * 256 + t];
    lds[t] = v;
    __syncthreads();
    for (int d = 1; d < 256; d <<= 1) {
        int mine = lds[t];
        int add = (t >= d) ? lds[t - d] : 0;
        __syncthreads();
        lds[t] = mine + add;
        __syncthreads();
    }
    int excl = lds[t] - v + partials[b];
    offsets[b * 256 + t] = excl;
    cursor[b * 256 + t] = excl;
    if (b == 255 && t == 255) offsets[N_NODES] = excl + v;   // == N_EDGES
}

__global__ void scatter_kernel(const int* __restrict__ src, const int* __restrict__ tgt,
                               int* __restrict__ cursor, int* __restrict__ sortedT) {
    int e = blockIdx.x * blockDim.x + threadIdx.x;
    if (e < N_EDGES) {
        int s = src[e];
        int pos = atomicAdd(&cursor[s], 1);
        sortedT[pos] = tgt[e];
    }
}

// ---------------- neighbor aggregation (wave per node, 4-deep MLP) ----------------
static __device__ __forceinline__ void acc8(float* a, uint4 v) {
    a[0] += bf16lo(v.x); a[1] += bf16hi(v.x);
    a[2] += bf16lo(v.y); a[3] += bf16hi(v.y);
    a[4] += bf16lo(v.z); a[5] += bf16hi(v.z);
    a[6] += bf16lo(v.w); a[7] += bf16hi(v.w);
}

__global__ void aggregate_kernel(const unsigned short* __restrict__ Xb,
                                 const int* __restrict__ offsets,
                                 const int* __restrict__ sortedT,
                                 unsigned short* __restrict__ agg) {
    int wave = (blockIdx.x * blockDim.x + threadIdx.x) >> 6;
    int lane = threadIdx.x & 63;
    if (wave >= N_NODES) return;
    int beg = offsets[wave], end = offsets[wave + 1];
    float a[8] = {0.f, 0.f, 0.f, 0.f, 0.f, 0.f, 0.f, 0.f};
    float b[8] = {0.f, 0.f, 0.f, 0.f, 0.f, 0.f, 0.f, 0.f};
    const uint4* F = (const uint4*)Xb;
    int i = beg;
    // 4 edges per iteration: 4 independent index loads, then 4 independent
    // 1KB gathers in flight -> 4x memory-level parallelism.
    for (; i + 4 <= end; i += 4) {
        int t0 = sortedT[i], t1 = sortedT[i + 1], t2 = sortedT[i + 2], t3 = sortedT[i + 3];
        uint4 v0 = F[t0 * 64 + lane];
        uint4 v1 = F[t1 * 64 + lane];
        uint4 v2 = F[t2 * 64 + lane];
        uint4 v3 = F[t3 * 64 + lane];
        acc8(a, v0); acc8(b, v1); acc8(a, v2); acc8(b, v3);
    }
    if (i + 2 <= end) {
        int t0 = sortedT[i], t1 = sortedT[i + 1];
        uint4 v0 = F[t0 * 64 + lane];
        uint4 v1 = F[t1 * 64 + lane];
        acc8(a, v0); acc8(b, v1);
        i += 2;
    }
    if (i < end) {
        int t0 = sortedT[i];
        uint4 v0 = F[t0 * 64 + lane];
        acc8(a, v0);
    }
#pragma unroll
    for (int k = 0; k < 8; ++k) a[k] += b[k];
    uint4 o;
    o.x = f2bf(a[0]) | (f2bf(a[1]) << 16);
    o.y = f2bf(a[2]) | (f2bf(a[3]) << 16);
    o.z = f2bf(a[4]) | (f2bf(a[5]) << 16);
    o.w = f2bf(a[6]) | (f2bf(a[7]) << 16);
    ((uint4*)agg)[wave * 64 + lane] = o;
}

// ---------------- fused GEMM + bias + ReLU + BN + row L2-normalize ----------------
// Block: 64 rows x 512 cols, 512 threads = 8 waves, wave w owns cols [w*64,w*64+64).
// Double-buffered stage-ahead (T3-min). Per kt: issue stage(kt+1) into the
// other buffer BEFORE computing kt; one __syncthreads per kt (its implicit
// vmcnt(0) drain lands after compute has hidden the load latency).
// B staging is wave-private (each wave stages only its own 64 B-rows; source
// stays row-contiguous so global coalescing is unchanged).
// LDS: A 2x8KB + B 2x64KB = 144KB -> 1 block/CU. ssm aliased into Abuf
// (safe: writes happen only after the loop-final barrier drains everything).
__global__ __launch_bounds__(512, 2) void fused_gemm_norm_kernel(
        const unsigned short* __restrict__ Xb,    // [N,512] bf16
        const unsigned short* __restrict__ agg,   // [N,512] bf16
        const unsigned short* __restrict__ Wb,    // [512,1024] bf16
        const float* __restrict__ bias,
        const float* __restrict__ gamma,
        const float* __restrict__ beta,
        const float* __restrict__ rmean,
        const float* __restrict__ rvar,
        float* __restrict__ out) {
    __shared__ uint4 Abuf[2][512];    // 2 x (64 rows x 8 chunks), XOR-swizzled image
    __shared__ uint4 Bbuf[2][4096];   // 2 x (8 waves x 64 rows x 8 chunks), per-wave slabs
    float (*ssm)[8] = reinterpret_cast<float (*)[8]>(&Abuf[0][0]);  // epilogue alias (2KB)

    const int t = threadIdx.x;
    const int m0 = blockIdx.x * 64;
    const int w = t >> 6, L = t & 63;
    const int ml = L & 15, quad = L >> 4;
    const int wn = w * 64;

    auto stage = [&](int buf, int kt) {
        const unsigned short* Asrc = (kt < 8) ? (Xb + kt * 64) : (agg + (kt - 8) * 64);
        // A tile: 64 rows x 64 k = 512 chunks, 1 per thread (block-cooperative)
        {
            int r = t >> 3, pp = t & 7;
            int p = pp ^ (r & 7);             // pre-swizzled source chunk
            const unsigned short* ga = Asrc + (m0 + r) * 512 + p * 8;
            char* la = (char*)&Abuf[buf][t & 448];   // wave-uniform base
            __builtin_amdgcn_global_load_lds(
                (const __attribute__((address_space(1))) unsigned int*)ga,
                (__attribute__((address_space(3))) unsigned int*)la, 16, 0, 0);
        }
        // B tile: wave-private 64 rows x 64 k = 512 chunks, 8 insts per wave
#pragma unroll
        for (int j = 0; j < 8; ++j) {
            int c = j * 64 + L;
            int rl = c >> 3, pp = c & 7;
            int p = pp ^ (rl & 7);
            const unsigned short* gb = Wb + (wn + rl) * 1024 + kt * 64 + p * 8;
            char* lb = (char*)&Bbuf[buf][w * 512 + j * 64];  // wave-uniform base
            __builtin_amdgcn_global_load_lds(
                (const __attribute__((address_space(1))) unsigned int*)gb,
                (__attribute__((address_space(3))) unsigned int*)lb, 16, 0, 0);
        }
    };

    f32x4 acc[4][4];
#pragma unroll
    for (int mi = 0; mi < 4; ++mi)
#pragma unroll
        for (int ni = 0; ni < 4; ++ni)
            acc[mi][ni] = (f32x4){0.f, 0.f, 0.f, 0.f};

    // prologue: stage kt=0 into buf0
    stage(0, 0);
    __syncthreads();   // implicit vmcnt(0) drain publishes buf0

    int cur = 0;
    for (int kt = 0; kt < 16; ++kt) {
        // stage-ahead: issue next tile's loads before computing this tile
        if (kt < 15) stage(cur ^ 1, kt + 1);
#pragma unroll
        for (int kc = 0; kc < 2; ++kc) {
            int g = kc * 4 + quad;
            short8 a[4], b[4];
#pragma unroll
            for (int mi = 0; mi < 4; ++mi) {
                int ra = mi * 16 + ml;
                a[mi] = *(const short8*)&Abuf[cur][ra * 8 + (g ^ (ra & 7))];
                int rl = mi * 16 + ml;
                b[mi] = *(const short8*)&Bbuf[cur][w * 512 + rl * 8 + (g ^ (rl & 7))];
            }
#pragma unroll
            for (int mi = 0; mi < 4; ++mi)
#pragma unroll
                for (int ni = 0; ni < 4; ++ni)
                    acc[mi][ni] = __builtin_amdgcn_mfma_f32_16x16x32_bf16(
                        a[mi], b[ni], acc[mi][ni], 0, 0, 0);
        }
        __syncthreads();   // drains this wave's stage(kt+1) loads + publishes
        cur ^= 1;
    }

    // ---- epilogue: bias + ReLU + BN (in registers), row sum-of-squares ----
    float bi[4], sc[4], sh[4];
#pragma unroll
    for (int ni = 0; ni < 4; ++ni) {
        int col = wn + ni * 16 + ml;
        bi[ni] = bias[col];
        sc[ni] = gamma[col] * __frsqrt_rn(rvar[col] + BN_EPS);
        sh[ni] = beta[col] - rmean[col] * sc[ni];
    }
    float ss[4][4];
#pragma unroll
    for (int mi = 0; mi < 4; ++mi)
#pragma unroll
        for (int r = 0; r < 4; ++r)
            ss[mi][r] = 0.f;
#pragma unroll
    for (int mi = 0; mi < 4; ++mi)
#pragma unroll
        for (int ni = 0; ni < 4; ++ni)
#pragma unroll
            for (int r = 0; r < 4; ++r) {
                float v = fmaxf(acc[mi][ni][r] + bi[ni], 0.f) * sc[ni] + sh[ni];
                acc[mi][ni][r] = v;
                ss[mi][r] += v * v;
            }
    // reduce over the 16 lanes (ml) that share a row
#pragma unroll
    for (int mi = 0; mi < 4; ++mi)
#pragma unroll
        for (int r = 0; r < 4; ++r) {
#pragma unroll
            for (int d = 1; d < 16; d <<= 1)
                ss[mi][r] += __shfl_xor(ss[mi][r], d);
        }
    if (ml == 0) {
#pragma unroll
        for (int mi = 0; mi < 4; ++mi)
#pragma unroll
            for (int r = 0; r < 4; ++r)
                ssm[mi * 16 + quad * 4 + r][w] = ss[mi][r];
    }
    __syncthreads();
    // ---- finish: total ss across 8 waves, scale, coalesced write ----
#pragma unroll
    for (int mi = 0; mi < 4; ++mi)
#pragma unroll
        for (int r = 0; r < 4; ++r) {
            int rl = mi * 16 + quad * 4 + r;
            const float4* sp = (const float4*)ssm[rl];
            float4 s0 = sp[0], s1 = sp[1];
            float tot = s0.x + s0.y + s0.z + s0.w + s1.x + s1.y + s1.z + s1.w;
            float inv = 1.f / (sqrtf(tot) + NORM_EPS);
            int m = m0 + rl;
#pragma unroll
            for (int ni = 0; ni < 4; ++ni)
                out[m * 512 + wn + ni * 16 + ml] = acc[mi][ni][r] * inv;
        }
}

extern "C" void kernel_launch(void* const* d_in, const int* in_sizes, int n_in,
                              void* d_out, int out_size, void* d_ws, size_t ws_size,
                              hipStream_t stream) {
    const float* features = (const float*)d_in[0];
    const int* edges      = (const int*)d_in[1];
    const float* W        = (const float*)d_in[2];
    const float* bias     = (const float*)d_in[3];
    const float* gamma    = (const float*)d_in[4];
    const float* beta     = (const float*)d_in[5];
    const float* rmean    = (const float*)d_in[6];
    const float* rvar     = (const float*)d_in[7];
    float* out = (float*)d_out;

    char* ws = (char*)d_ws;
    int* counts   = (int*)(ws);                              // 256 KB
    int* offsets  = (int*)(ws + 0x100000);                   // 256 KB + 4
    int* cursor   = (int*)(ws + 0x200000);                   // 256 KB
    int* partials = (int*)(ws + 0x280000);                   // 1 KB
    int* sortedT  = (int*)(ws + 0x300000);                   // 2 MB
    unsigned short* Wb  = (unsigned short*)(ws + 0x500000);  // 1 MB bf16 W
    unsigned short* Xb  = (unsigned short*)(ws + 0x600000);  // 64 MB bf16 features
    unsigned short* agg = (unsigned short*)(ws + 0x4600000); // 64 MB bf16 aggregated

    const int* src = edges;
    const int* tgt = edges + N_EDGES;

    hipMemsetAsync(counts, 0, N_NODES * sizeof(int), stream);
    hist_kernel<<<N_EDGES / 256, 256, 0, stream>>>(src, counts);
    scan_partial<<<256, 256, 0, stream>>>(counts, partials);
    scan_base<<<1, 256, 0, stream>>>(partials);
    scan_final<<<256, 256, 0, stream>>>(counts, partials, offsets, cursor);
    scatter_kernel<<<N_EDGES / 256, 256, 0, stream>>>(src, tgt, cursor, sortedT);
    convert_kernel<<<(N_NODES * DIM / 8) / 256, 256, 0, stream>>>(features, Xb, N_NODES * DIM / 8);
    convert_kernel<<<(DIM * 2 * DIM / 8) / 256, 256, 0, stream>>>(W, Wb, DIM * 2 * DIM / 8);
    aggregate_kernel<<<N_NODES / 4, 256, 0, stream>>>(Xb, offsets, sortedT, agg);
    fused_gemm_norm_kernel<<<N_NODES / 64, 512, 0, stream>>>(
        Xb, agg, Wb, bias, gamma, beta, rmean, rvar, out);
}

// Round 4
// 459.146 us; speedup vs baseline: 1.0780x; 1.0780x over previous
//
#include <hip/hip_runtime.h>
#include <hip/hip_bf16.h>

#define N_NODES 65536
#define DIM 512
#define N_EDGES 524288
#define BN_EPS 1e-5f
#define NORM_EPS 1e-6f

typedef __attribute__((ext_vector_type(8))) short short8;
typedef __attribute__((ext_vector_type(4))) float f32x4;

static __device__ __forceinline__ unsigned f2bf(float f) {
    union { float f; unsigned u; } c; c.f = f;
    unsigned u = c.u;
    return (u + 0x7fffu + ((u >> 16) & 1u)) >> 16;
}
static __device__ __forceinline__ float bf16lo(unsigned u) {
    union { unsigned u; float f; } c; c.u = u << 16; return c.f;
}
static __device__ __forceinline__ float bf16hi(unsigned u) {
    union { unsigned u; float f; } c; c.u = u & 0xffff0000u; return c.f;
}
static __device__ __forceinline__ uint4 pack8(float4 a, float4 b) {
    uint4 o;
    o.x = f2bf(a.x) | (f2bf(a.y) << 16);
    o.y = f2bf(a.z) | (f2bf(a.w) << 16);
    o.z = f2bf(b.x) | (f2bf(b.y) << 16);
    o.w = f2bf(b.z) | (f2bf(b.w) << 16);
    return o;
}

// ---------------- fp32 -> bf16 convert (8 elems/thread) ----------------
__global__ void convert_kernel(const float* __restrict__ src,
                               unsigned short* __restrict__ dst, int n8) {
    int i = blockIdx.x * blockDim.x + threadIdx.x;
    if (i < n8) {
        const float4* s = (const float4*)src + i * 2;
        float4 f0 = s[0], f1 = s[1];
        ((uint4*)dst)[i] = pack8(f0, f1);
    }
}

// ---------------- CSR build ----------------
__global__ void hist_kernel(const int* __restrict__ src, int* __restrict__ counts) {
    int e = blockIdx.x * blockDim.x + threadIdx.x;
    if (e < N_EDGES) atomicAdd(&counts[src[e]], 1);
}

__global__ void scan_partial(const int* __restrict__ counts, int* __restrict__ partials) {
    __shared__ int ws[4];
    int t = threadIdx.x;
    int v = counts[blockIdx.x * 256 + t];
#pragma unroll
    for (int d = 1; d < 64; d <<= 1) v += __shfl_xor(v, d);
    if ((t & 63) == 0) ws[t >> 6] = v;
    __syncthreads();
    if (t == 0) partials[blockIdx.x] = ws[0] + ws[1] + ws[2] + ws[3];
}

__global__ void scan_base(int* __restrict__ partials) {
    __shared__ int lds[256];
    int t = threadIdx.x;
    int v = partials[t];
    lds[t] = v;
    __syncthreads();
    for (int d = 1; d < 256; d <<= 1) {
        int mine = lds[t];
        int add = (t >= d) ? lds[t - d] : 0;
        __syncthreads();
        lds[t] = mine + add;
        __syncthreads();
    }
    partials[t] = lds[t] - v;   // exclusive
}

__global__ void scan_final(const int* __restrict__ counts,
                           const int* __restrict__ partials,
                           int* __restrict__ offsets, int* __restrict__ cursor) {
    __shared__ int lds[256];
    int t = threadIdx.x, b = blockIdx.x;
    int v = counts[b * 256 + t];
    lds[t] = v;
    __syncthreads();
    for (int d = 1; d < 256; d <<= 1) {
        int mine = lds[t];
        int add = (t >= d) ? lds[t - d] : 0;
        __syncthreads();
        lds[t] = mine + add;
        __syncthreads();
    }
    int excl = lds[t] - v + partials[b];
    offsets[b * 256 + t] = excl;
    cursor[b * 256 + t] = excl;
    if (b == 255 && t == 255) offsets[N_NODES] = excl + v;   // == N_EDGES
}

__global__ void scatter_kernel(const int* __restrict__ src, const int* __restrict__ tgt,
                               int* __restrict__ cursor, int* __restrict__ sortedT) {
    int e = blockIdx.x * blockDim.x + threadIdx.x;
    if (e < N_EDGES) {
        int s = src[e];
        int pos = atomicAdd(&cursor[s], 1);
        sortedT[pos] = tgt[e];
    }
}

// ---------------- neighbor aggregation (wave per node, 4-deep MLP) ----------------
static __device__ __forceinline__ void acc8(float* a, uint4 v) {
    a[0] += bf16lo(v.x); a[1] += bf16hi(v.x);
    a[2] += bf16lo(v.y); a[3] += bf16hi(v.y);
    a[4] += bf16lo(v.z); a[5] += bf16hi(v.z);
    a[6] += bf16lo(v.w); a[7] += bf16hi(v.w);
}

__global__ void aggregate_kernel(const unsigned short* __restrict__ Xb,
                                 const int* __restrict__ offsets,
                                 const int* __restrict__ sortedT,
                                 unsigned short* __restrict__ agg) {
    int wave = (blockIdx.x * blockDim.x + threadIdx.x) >> 6;
    int lane = threadIdx.x & 63;
    if (wave >= N_NODES) return;
    int beg = offsets[wave], end = offsets[wave + 1];
    float a[8] = {0.f, 0.f, 0.f, 0.f, 0.f, 0.f, 0.f, 0.f};
    float b[8] = {0.f, 0.f, 0.f, 0.f, 0.f, 0.f, 0.f, 0.f};
    const uint4* F = (const uint4*)Xb;
    int i = beg;
    for (; i + 4 <= end; i += 4) {
        int t0 = sortedT[i], t1 = sortedT[i + 1], t2 = sortedT[i + 2], t3 = sortedT[i + 3];
        uint4 v0 = F[t0 * 64 + lane];
        uint4 v1 = F[t1 * 64 + lane];
        uint4 v2 = F[t2 * 64 + lane];
        uint4 v3 = F[t3 * 64 + lane];
        acc8(a, v0); acc8(b, v1); acc8(a, v2); acc8(b, v3);
    }
    if (i + 2 <= end) {
        int t0 = sortedT[i], t1 = sortedT[i + 1];
        uint4 v0 = F[t0 * 64 + lane];
        uint4 v1 = F[t1 * 64 + lane];
        acc8(a, v0); acc8(b, v1);
        i += 2;
    }
    if (i < end) {
        int t0 = sortedT[i];
        uint4 v0 = F[t0 * 64 + lane];
        acc8(a, v0);
    }
#pragma unroll
    for (int k = 0; k < 8; ++k) a[k] += b[k];
    uint4 o;
    o.x = f2bf(a[0]) | (f2bf(a[1]) << 16);
    o.y = f2bf(a[2]) | (f2bf(a[3]) << 16);
    o.z = f2bf(a[4]) | (f2bf(a[5]) << 16);
    o.w = f2bf(a[6]) | (f2bf(a[7]) << 16);
    ((uint4*)agg)[wave * 64 + lane] = o;
}

// ---------------- fused GEMM + bias + ReLU + BN + row L2-normalize ----------------
// Block: 128 rows x 512 cols (full output rows -> norm fusable), 1024 thr = 16 waves,
// wave grid 2(M)x8(N), wave tile 64x64 (acc 4x4 -> VGPR ~100, 4 waves/SIMD, all
// 16 waves resident on one CU).
// vs round-1 (M=64): B L2->LDS traffic halves (1GB -> 512MB), staging 9 -> 5
// loads/thread/kt.
// Pipeline (T3/T4 minimum): double-buffered LDS; per kt issue stage(kt+1), then
//   s_waitcnt vmcnt(5)  -- tile-kt's 5 loads landed; kt+1's 5 stay IN FLIGHT
//   s_barrier           -- raw: does NOT drain vmcnt (unlike __syncthreads)
//   compute(kt)
//   s_waitcnt lgkmcnt(0) -- DS queue empty before buffer can be overwritten
//   s_barrier
// The L2 weight stream never drains -> removes round-3's whole-CU stall.
// LDS: A 2x16KB + B 2x64KB = 160KB (gfx950 max). ssm aliased into Abuf[0].
__global__ __launch_bounds__(1024, 4) void fused_gemm_norm_kernel(
        const unsigned short* __restrict__ Xb,    // [N,512] bf16
        const unsigned short* __restrict__ agg,   // [N,512] bf16
        const unsigned short* __restrict__ Wb,    // [512,1024] bf16 ([col][k])
        const float* __restrict__ bias,
        const float* __restrict__ gamma,
        const float* __restrict__ beta,
        const float* __restrict__ rmean,
        const float* __restrict__ rvar,
        float* __restrict__ out) {
    __shared__ uint4 Abuf[2][1024];   // 2 x (128 rows x 8 chunks), XOR-swizzled image
    __shared__ uint4 Bbuf[2][4096];   // 2 x (512 rows x 8 chunks), XOR-swizzled image
    float (*ssm)[8] = reinterpret_cast<float (*)[8]>(&Abuf[0][0]);  // 128x8 f32 (4KB alias)

    const int t = threadIdx.x;
    const int m0 = blockIdx.x * 128;
    const int w = t >> 6, L = t & 63;
    const int ml = L & 15, quad = L >> 4;
    const int wm = (w >> 3) * 64;     // 0 or 64
    const int wn = (w & 7) * 64;      // 0..448

    auto stage = [&](int buf, int kt) {
        const unsigned short* Asrc = (kt < 8) ? (Xb + kt * 64) : (agg + (kt - 8) * 64);
        // A tile: 128 rows x 8 chunks = 1024 chunks, 1 per thread
        {
            int r = t >> 3, pp = t & 7;
            int p = pp ^ (r & 7);              // pre-swizzled source chunk
            const unsigned short* ga = Asrc + (m0 + r) * 512 + p * 8;
            char* la = (char*)&Abuf[buf][t & 960];   // wave-uniform base
            __builtin_amdgcn_global_load_lds(
                (const __attribute__((address_space(1))) unsigned int*)ga,
                (__attribute__((address_space(3))) unsigned int*)la, 16, 0, 0);
        }
        // B tile: 512 rows x 8 chunks = 4096 chunks, 4 per thread
#pragma unroll
        for (int j = 0; j < 4; ++j) {
            int c = j * 1024 + t;
            int r = c >> 3, pp = c & 7;
            int p = pp ^ (r & 7);
            const unsigned short* gb = Wb + r * 1024 + kt * 64 + p * 8;
            char* lb = (char*)&Bbuf[buf][j * 1024 + (t & 960)];  // wave-uniform base
            __builtin_amdgcn_global_load_lds(
                (const __attribute__((address_space(1))) unsigned int*)gb,
                (__attribute__((address_space(3))) unsigned int*)lb, 16, 0, 0);
        }
    };

    f32x4 acc[4][4];
#pragma unroll
    for (int mi = 0; mi < 4; ++mi)
#pragma unroll
        for (int ni = 0; ni < 4; ++ni)
            acc[mi][ni] = (f32x4){0.f, 0.f, 0.f, 0.f};

    // prologue: stage kt=0 into buf0 (5 loads in flight; waited inside the loop)
    stage(0, 0);

    int cur = 0;
    for (int kt = 0; kt < 16; ++kt) {
        if (kt < 15) {
            stage(cur ^ 1, kt + 1);   // +5 loads -> 10 outstanding
            asm volatile("s_waitcnt vmcnt(5)" ::: "memory");  // tile-kt's 5 landed
        } else {
            asm volatile("s_waitcnt vmcnt(0)" ::: "memory");  // last tile: drain
        }
        __builtin_amdgcn_s_barrier();    // raw: kt+1's loads stay in flight
#pragma unroll
        for (int kc = 0; kc < 2; ++kc) {
            int g = kc * 4 + quad;
            short8 a[4], b[4];
#pragma unroll
            for (int x = 0; x < 4; ++x) {
                int ra = wm + x * 16 + ml;
                a[x] = *(const short8*)&Abuf[cur][ra * 8 + (g ^ (ra & 7))];
                int rb = wn + x * 16 + ml;
                b[x] = *(const short8*)&Bbuf[cur][rb * 8 + (g ^ (rb & 7))];
            }
#pragma unroll
            for (int mi = 0; mi < 4; ++mi)
#pragma unroll
                for (int ni = 0; ni < 4; ++ni)
                    acc[mi][ni] = __builtin_amdgcn_mfma_f32_16x16x32_bf16(
                        a[mi], b[ni], acc[mi][ni], 0, 0, 0);
        }
        asm volatile("s_waitcnt lgkmcnt(0)" ::: "memory");  // DS queue empty
        __builtin_amdgcn_s_barrier();    // buf[cur] now safe to overwrite
        cur ^= 1;
    }

    // ---- epilogue: bias + ReLU + BN (in registers), row sum-of-squares ----
    float bi[4], sc[4], sh[4];
#pragma unroll
    for (int ni = 0; ni < 4; ++ni) {
        int col = wn + ni * 16 + ml;
        bi[ni] = bias[col];
        sc[ni] = gamma[col] * __frsqrt_rn(rvar[col] + BN_EPS);
        sh[ni] = beta[col] - rmean[col] * sc[ni];
    }
    float ss[4][4];
#pragma unroll
    for (int mi = 0; mi < 4; ++mi)
#pragma unroll
        for (int r = 0; r < 4; ++r)
            ss[mi][r] = 0.f;
#pragma unroll
    for (int mi = 0; mi < 4; ++mi)
#pragma unroll
        for (int ni = 0; ni < 4; ++ni)
#pragma unroll
            for (int r = 0; r < 4; ++r) {
                float v = fmaxf(acc[mi][ni][r] + bi[ni], 0.f) * sc[ni] + sh[ni];
                acc[mi][ni][r] = v;
                ss[mi][r] += v * v;
            }
    // reduce over the 16 lanes (ml) that share a row
#pragma unroll
    for (int mi = 0; mi < 4; ++mi)
#pragma unroll
        for (int r = 0; r < 4; ++r) {
#pragma unroll
            for (int d = 1; d < 16; d <<= 1)
                ss[mi][r] += __shfl_xor(ss[mi][r], d);
        }
    if (ml == 0) {
#pragma unroll
        for (int mi = 0; mi < 4; ++mi)
#pragma unroll
            for (int r = 0; r < 4; ++r)
                ssm[wm + mi * 16 + quad * 4 + r][w & 7] = ss[mi][r];
    }
    __syncthreads();
    // ---- finish: total ss across the 8 n-waves of this row group, scale, write ----
#pragma unroll
    for (int mi = 0; mi < 4; ++mi)
#pragma unroll
        for (int r = 0; r < 4; ++r) {
            int rl = wm + mi * 16 + quad * 4 + r;
            const float4* sp = (const float4*)ssm[rl];
            float4 s0 = sp[0], s1 = sp[1];
            float tot = s0.x + s0.y + s0.z + s0.w + s1.x + s1.y + s1.z + s1.w;
            float inv = 1.f / (sqrtf(tot) + NORM_EPS);
            int m = m0 + rl;
#pragma unroll
            for (int ni = 0; ni < 4; ++ni)
                out[m * 512 + wn + ni * 16 + ml] = acc[mi][ni][r] * inv;
        }
}

extern "C" void kernel_launch(void* const* d_in, const int* in_sizes, int n_in,
                              void* d_out, int out_size, void* d_ws, size_t ws_size,
                              hipStream_t stream) {
    const float* features = (const float*)d_in[0];
    const int* edges      = (const int*)d_in[1];
    const float* W        = (const float*)d_in[2];
    const float* bias     = (const float*)d_in[3];
    const float* gamma    = (const float*)d_in[4];
    const float* beta     = (const float*)d_in[5];
    const float* rmean    = (const float*)d_in[6];
    const float* rvar     = (const float*)d_in[7];
    float* out = (float*)d_out;

    char* ws = (char*)d_ws;
    int* counts   = (int*)(ws);                              // 256 KB
    int* offsets  = (int*)(ws + 0x100000);                   // 256 KB + 4
    int* cursor   = (int*)(ws + 0x200000);                   // 256 KB
    int* partials = (int*)(ws + 0x280000);                   // 1 KB
    int* sortedT  = (int*)(ws + 0x300000);                   // 2 MB
    unsigned short* Wb  = (unsigned short*)(ws + 0x500000);  // 1 MB bf16 W
    unsigned short* Xb  = (unsigned short*)(ws + 0x600000);  // 64 MB bf16 features
    unsigned short* agg = (unsigned short*)(ws + 0x4600000); // 64 MB bf16 aggregated

    const int* src = edges;
    const int* tgt = edges + N_EDGES;

    hipMemsetAsync(counts, 0, N_NODES * sizeof(int), stream);
    hist_kernel<<<N_EDGES / 256, 256, 0, stream>>>(src, counts);
    scan_partial<<<256, 256, 0, stream>>>(counts, partials);
    scan_base<<<1, 256, 0, stream>>>(partials);
    scan_final<<<256, 256, 0, stream>>>(counts, partials, offsets, cursor);
    scatter_kernel<<<N_EDGES / 256, 256, 0, stream>>>(src, tgt, cursor, sortedT);
    convert_kernel<<<(N_NODES * DIM / 8) / 256, 256, 0, stream>>>(features, Xb, N_NODES * DIM / 8);
    convert_kernel<<<(DIM * 2 * DIM / 8) / 256, 256, 0, stream>>>(W, Wb, DIM * 2 * DIM / 8);
    aggregate_kernel<<<N_NODES / 4, 256, 0, stream>>>(Xb, offsets, sortedT, agg);
    fused_gemm_norm_kernel<<<N_NODES / 128, 1024, 0, stream>>>(
        Xb, agg, Wb, bias, gamma, beta, rmean, rvar, out);
}

// Round 6
// 441.006 us; speedup vs baseline: 1.1224x; 1.0411x over previous
//
#include <hip/hip_runtime.h>
#include <hip/hip_bf16.h>

#define N_NODES 65536
#define DIM 512
#define N_EDGES 524288
#define BN_EPS 1e-5f
#define NORM_EPS 1e-6f

typedef __attribute__((ext_vector_type(8))) short short8;
typedef __attribute__((ext_vector_type(4))) float f32x4;

static __device__ __forceinline__ unsigned f2bf(float f) {
    union { float f; unsigned u; } c; c.f = f;
    unsigned u = c.u;
    return (u + 0x7fffu + ((u >> 16) & 1u)) >> 16;
}
static __device__ __forceinline__ float bf16lo(unsigned u) {
    union { unsigned u; float f; } c; c.u = u << 16; return c.f;
}
static __device__ __forceinline__ float bf16hi(unsigned u) {
    union { unsigned u; float f; } c; c.u = u & 0xffff0000u; return c.f;
}
static __device__ __forceinline__ uint4 pack8(float4 a, float4 b) {
    uint4 o;
    o.x = f2bf(a.x) | (f2bf(a.y) << 16);
    o.y = f2bf(a.z) | (f2bf(a.w) << 16);
    o.z = f2bf(b.x) | (f2bf(b.y) << 16);
    o.w = f2bf(b.z) | (f2bf(b.w) << 16);
    return o;
}

// ---------------- merged prep: convert features, convert W, histogram ----------------
// blockIdx partition: [0,16384) features->bf16, [16384,16640) W->bf16,
// [16640,18688) edge histogram. Independent work in one launch: convert
// streaming and hist atomics cover each other's latency; saves 2 launch gaps.
#define NB_CONVF 16384   // 65536*512/8/256
#define NB_CONVW 256     // 512*1024/8/256  (FIX: was 512 -> OOB read of W + Xb trample)
#define NB_HIST  2048    // 524288/256

__global__ void prep_kernel(const float* __restrict__ features,
                            unsigned short* __restrict__ Xb,
                            const float* __restrict__ W,
                            unsigned short* __restrict__ Wb,
                            const int* __restrict__ src,
                            int* __restrict__ counts) {
    int b = blockIdx.x;
    if (b < NB_CONVF) {
        int i = b * 256 + threadIdx.x;
        const float4* s = (const float4*)features + i * 2;
        ((uint4*)Xb)[i] = pack8(s[0], s[1]);
    } else if (b < NB_CONVF + NB_CONVW) {
        int i = (b - NB_CONVF) * 256 + threadIdx.x;
        const float4* s = (const float4*)W + i * 2;
        ((uint4*)Wb)[i] = pack8(s[0], s[1]);
    } else {
        int e = (b - NB_CONVF - NB_CONVW) * 256 + threadIdx.x;
        atomicAdd(&counts[src[e]], 1);
    }
}

// stage 1: per-block (256 counts) sums
__global__ void scan_partial(const int* __restrict__ counts, int* __restrict__ partials) {
    __shared__ int ws[4];
    int t = threadIdx.x;
    int v = counts[blockIdx.x * 256 + t];
#pragma unroll
    for (int d = 1; d < 64; d <<= 1) v += __shfl_xor(v, d);
    if ((t & 63) == 0) ws[t >> 6] = v;
    __syncthreads();
    if (t == 0) partials[blockIdx.x] = ws[0] + ws[1] + ws[2] + ws[3];
}

// stage 2+3 merged: every block redundantly scans the 256 partials in LDS
// (1KB read) AND scans its own 256 counts; replaces the single-block
// scan_base kernel (whole-GPU idle) + a launch gap.
__global__ void scan_final2(const int* __restrict__ counts,
                            const int* __restrict__ partials,
                            int* __restrict__ offsets, int* __restrict__ cursor) {
    __shared__ int lds[256];
    __shared__ int pl[256];
    int t = threadIdx.x, b = blockIdx.x;
    int v = counts[b * 256 + t];
    lds[t] = v;
    pl[t] = partials[t];
    __syncthreads();
    for (int d = 1; d < 256; d <<= 1) {
        int mine = lds[t];
        int add = (t >= d) ? lds[t - d] : 0;
        int pm = pl[t];
        int pa = (t >= d) ? pl[t - d] : 0;
        __syncthreads();
        lds[t] = mine + add;
        pl[t] = pm + pa;
        __syncthreads();
    }
    int base = (b > 0) ? pl[b - 1] : 0;    // exclusive prefix of partials
    int excl = lds[t] - v + base;
    offsets[b * 256 + t] = excl;
    cursor[b * 256 + t] = excl;
    if (b == 255 && t == 255) offsets[N_NODES] = excl + v;   // == N_EDGES
}

__global__ void scatter_kernel(const int* __restrict__ src, const int* __restrict__ tgt,
                               int* __restrict__ cursor, int* __restrict__ sortedT) {
    int e = blockIdx.x * blockDim.x + threadIdx.x;
    if (e < N_EDGES) {
        int s = src[e];
        int pos = atomicAdd(&cursor[s], 1);
        sortedT[pos] = tgt[e];
    }
}

// ---------------- neighbor aggregation (wave per node, 4-deep MLP) ----------------
static __device__ __forceinline__ void acc8(float* a, uint4 v) {
    a[0] += bf16lo(v.x); a[1] += bf16hi(v.x);
    a[2] += bf16lo(v.y); a[3] += bf16hi(v.y);
    a[4] += bf16lo(v.z); a[5] += bf16hi(v.z);
    a[6] += bf16lo(v.w); a[7] += bf16hi(v.w);
}

__global__ void aggregate_kernel(const unsigned short* __restrict__ Xb,
                                 const int* __restrict__ offsets,
                                 const int* __restrict__ sortedT,
                                 unsigned short* __restrict__ agg) {
    int wave = (blockIdx.x * blockDim.x + threadIdx.x) >> 6;
    int lane = threadIdx.x & 63;
    if (wave >= N_NODES) return;
    int beg = offsets[wave], end = offsets[wave + 1];
    float a[8] = {0.f, 0.f, 0.f, 0.f, 0.f, 0.f, 0.f, 0.f};
    float b[8] = {0.f, 0.f, 0.f, 0.f, 0.f, 0.f, 0.f, 0.f};
    const uint4* F = (const uint4*)Xb;
    int i = beg;
    for (; i + 4 <= end; i += 4) {
        int t0 = sortedT[i], t1 = sortedT[i + 1], t2 = sortedT[i + 2], t3 = sortedT[i + 3];
        uint4 v0 = F[t0 * 64 + lane];
        uint4 v1 = F[t1 * 64 + lane];
        uint4 v2 = F[t2 * 64 + lane];
        uint4 v3 = F[t3 * 64 + lane];
        acc8(a, v0); acc8(b, v1); acc8(a, v2); acc8(b, v3);
    }
    if (i + 2 <= end) {
        int t0 = sortedT[i], t1 = sortedT[i + 1];
        uint4 v0 = F[t0 * 64 + lane];
        uint4 v1 = F[t1 * 64 + lane];
        acc8(a, v0); acc8(b, v1);
        i += 2;
    }
    if (i < end) {
        int t0 = sortedT[i];
        uint4 v0 = F[t0 * 64 + lane];
        acc8(a, v0);
    }
#pragma unroll
    for (int k = 0; k < 8; ++k) a[k] += b[k];
    uint4 o;
    o.x = f2bf(a[0]) | (f2bf(a[1]) << 16);
    o.y = f2bf(a[2]) | (f2bf(a[3]) << 16);
    o.z = f2bf(a[4]) | (f2bf(a[5]) << 16);
    o.w = f2bf(a[6]) | (f2bf(a[7]) << 16);
    ((uint4*)agg)[wave * 64 + lane] = o;
}

// ---------------- fused GEMM + bias + ReLU + BN + row L2-normalize ----------------
// Round-1 proven structure (89.7us): 64 rows x 512 cols, 512 thr = 8 waves,
// single-buffered LDS (74KB -> 2 blocks/CU; inter-block TLP hides the
// stage->drain->compute serialization better than any 1-block pipeline tried).
// Tweak vs round-1: bias/BN params hoisted above the K-loop.
__global__ __launch_bounds__(512, 4) void fused_gemm_norm_kernel(
        const unsigned short* __restrict__ Xb,    // [N,512] bf16
        const unsigned short* __restrict__ agg,   // [N,512] bf16
        const unsigned short* __restrict__ Wb,    // [512,1024] bf16
        const float* __restrict__ bias,
        const float* __restrict__ gamma,
        const float* __restrict__ beta,
        const float* __restrict__ rmean,
        const float* __restrict__ rvar,
        float* __restrict__ out) {
    __shared__ uint4 Alds[512];    // 64 rows x 8 chunks(16B), XOR-swizzled image (8 KB)
    __shared__ uint4 Blds[4096];   // 512 rows x 8 chunks(16B), XOR-swizzled image (64 KB)
    __shared__ float ssm[64][8];   // per-row, per-wave partial sum of squares (2 KB)

    const int t = threadIdx.x;
    const int m0 = blockIdx.x * 64;
    const int w = t >> 6, L = t & 63;
    const int ml = L & 15, quad = L >> 4;
    const int wn = w * 64;

    // epilogue params hoisted above the K-loop
    float bi[4], sc[4], sh[4];
#pragma unroll
    for (int ni = 0; ni < 4; ++ni) {
        int col = wn + ni * 16 + ml;
        bi[ni] = bias[col];
        sc[ni] = gamma[col] * __frsqrt_rn(rvar[col] + BN_EPS);
        sh[ni] = beta[col] - rmean[col] * sc[ni];
    }

    f32x4 acc[4][4];
#pragma unroll
    for (int mi = 0; mi < 4; ++mi)
#pragma unroll
        for (int ni = 0; ni < 4; ++ni)
            acc[mi][ni] = (f32x4){0.f, 0.f, 0.f, 0.f};

    for (int kt = 0; kt < 16; ++kt) {
        const unsigned short* Asrc = (kt < 8) ? (Xb + kt * 64) : (agg + (kt - 8) * 64);
        __syncthreads();
        // ---- A tile: 64 rows x 64 k = 512 chunks, 1 per thread ----
        {
            int r = t >> 3, pp = t & 7;
            int p = pp ^ (r & 7);            // pre-swizzled source chunk
            const unsigned short* ga = Asrc + (m0 + r) * 512 + p * 8;
            char* la = (char*)Alds + (t & 448) * 16;   // wave-uniform base
            __builtin_amdgcn_global_load_lds(
                (const __attribute__((address_space(1))) unsigned int*)ga,
                (__attribute__((address_space(3))) unsigned int*)la, 16, 0, 0);
        }
        // ---- B tile: 512 rows x 64 k = 4096 chunks, 8 per thread ----
#pragma unroll
        for (int j = 0; j < 8; ++j) {
            int c = j * 512 + t;
            int r = c >> 3, pp = c & 7;
            int p = pp ^ (r & 7);
            const unsigned short* gb = Wb + r * 1024 + kt * 64 + p * 8;
            char* lb = (char*)Blds + (j * 512 + (t & 448)) * 16;
            __builtin_amdgcn_global_load_lds(
                (const __attribute__((address_space(1))) unsigned int*)gb,
                (__attribute__((address_space(3))) unsigned int*)lb, 16, 0, 0);
        }
        __syncthreads();
#pragma unroll
        for (int kc = 0; kc < 2; ++kc) {
            int g = kc * 4 + quad;
            short8 a[4], b[4];
#pragma unroll
            for (int mi = 0; mi < 4; ++mi) {
                int ra = mi * 16 + ml;
                a[mi] = *(const short8*)&Alds[ra * 8 + (g ^ (ra & 7))];
                int rb = wn + mi * 16 + ml;
                b[mi] = *(const short8*)&Blds[rb * 8 + (g ^ (rb & 7))];
            }
#pragma unroll
            for (int mi = 0; mi < 4; ++mi)
#pragma unroll
                for (int ni = 0; ni < 4; ++ni)
                    acc[mi][ni] = __builtin_amdgcn_mfma_f32_16x16x32_bf16(
                        a[mi], b[ni], acc[mi][ni], 0, 0, 0);
        }
    }

    // ---- epilogue: bias + ReLU + BN (in registers), row sum-of-squares ----
    float ss[4][4];
#pragma unroll
    for (int mi = 0; mi < 4; ++mi)
#pragma unroll
        for (int r = 0; r < 4; ++r)
            ss[mi][r] = 0.f;
#pragma unroll
    for (int mi = 0; mi < 4; ++mi)
#pragma unroll
        for (int ni = 0; ni < 4; ++ni)
#pragma unroll
            for (int r = 0; r < 4; ++r) {
                float v = fmaxf(acc[mi][ni][r] + bi[ni], 0.f) * sc[ni] + sh[ni];
                acc[mi][ni][r] = v;
                ss[mi][r] += v * v;
            }
    // reduce over the 16 lanes (ml) that share a row
#pragma unroll
    for (int mi = 0; mi < 4; ++mi)
#pragma unroll
        for (int r = 0; r < 4; ++r) {
#pragma unroll
            for (int d = 1; d < 16; d <<= 1)
                ss[mi][r] += __shfl_xor(ss[mi][r], d);
        }
    if (ml == 0) {
#pragma unroll
        for (int mi = 0; mi < 4; ++mi)
#pragma unroll
            for (int r = 0; r < 4; ++r)
                ssm[mi * 16 + quad * 4 + r][w] = ss[mi][r];
    }
    __syncthreads();
    // ---- finish: total ss across 8 waves, scale, coalesced write ----
#pragma unroll
    for (int mi = 0; mi < 4; ++mi)
#pragma unroll
        for (int r = 0; r < 4; ++r) {
            int rl = mi * 16 + quad * 4 + r;
            const float4* sp = (const float4*)ssm[rl];
            float4 s0 = sp[0], s1 = sp[1];
            float tot = s0.x + s0.y + s0.z + s0.w + s1.x + s1.y + s1.z + s1.w;
            float inv = 1.f / (sqrtf(tot) + NORM_EPS);
            int m = m0 + rl;
#pragma unroll
            for (int ni = 0; ni < 4; ++ni)
                out[m * 512 + wn + ni * 16 + ml] = acc[mi][ni][r] * inv;
        }
}

extern "C" void kernel_launch(void* const* d_in, const int* in_sizes, int n_in,
                              void* d_out, int out_size, void* d_ws, size_t ws_size,
                              hipStream_t stream) {
    const float* features = (const float*)d_in[0];
    const int* edges      = (const int*)d_in[1];
    const float* W        = (const float*)d_in[2];
    const float* bias     = (const float*)d_in[3];
    const float* gamma    = (const float*)d_in[4];
    const float* beta     = (const float*)d_in[5];
    const float* rmean    = (const float*)d_in[6];
    const float* rvar     = (const float*)d_in[7];
    float* out = (float*)d_out;

    char* ws = (char*)d_ws;
    int* counts   = (int*)(ws);                              // 256 KB
    int* offsets  = (int*)(ws + 0x100000);                   // 256 KB + 4
    int* cursor   = (int*)(ws + 0x200000);                   // 256 KB
    int* partials = (int*)(ws + 0x280000);                   // 1 KB
    int* sortedT  = (int*)(ws + 0x300000);                   // 2 MB
    unsigned short* Wb  = (unsigned short*)(ws + 0x500000);  // 1 MB bf16 W
    unsigned short* Xb  = (unsigned short*)(ws + 0x600000);  // 64 MB bf16 features
    unsigned short* agg = (unsigned short*)(ws + 0x4600000); // 64 MB bf16 aggregated

    const int* src = edges;
    const int* tgt = edges + N_EDGES;

    hipMemsetAsync(counts, 0, N_NODES * sizeof(int), stream);
    prep_kernel<<<NB_CONVF + NB_CONVW + NB_HIST, 256, 0, stream>>>(
        features, Xb, W, Wb, src, counts);
    scan_partial<<<256, 256, 0, stream>>>(counts, partials);
    scan_final2<<<256, 256, 0, stream>>>(counts, partials, offsets, cursor);
    scatter_kernel<<<N_EDGES / 256, 256, 0, stream>>>(src, tgt, cursor, sortedT);
    aggregate_kernel<<<N_NODES / 4, 256, 0, stream>>>(Xb, offsets, sortedT, agg);
    fused_gemm_norm_kernel<<<N_NODES / 64, 512, 0, stream>>>(
        Xb, agg, Wb, bias, gamma, beta, rmean, rvar, out);
}